// Round 12
// baseline (184.574 us; speedup 1.0000x reference)
//
#include <hip/hip_runtime.h>
#include <math.h>

#define NB 8
#define NT 2048
#define NC 256
#define NV 1024
#define BT (NB*NT)   // 16384 rows

typedef __attribute__((ext_vector_type(8)))  short bf16x8;
typedef __attribute__((ext_vector_type(8)))  short short8v;
typedef __attribute__((ext_vector_type(16))) float f32x16;

// ---- workspace byte offsets (total: 49,184 B; ws >= 77,856 proven) ----
#define HIST_OFF  0        // float[1024] (zeroed)
#define EN_OFF    4096     // float[1024] ||e||^2
#define CPART_OFF 8192     // float[1024] commitment partials
#define MPART_OFF 12288    // float[1024] mask partials
#define ORD_OFF   16384    // ushort[16384] (positions < 2048)
#define KC_OFF    49152    // int[8]
#define WS_REQ    49184

// truncated-bf16 limb: returns float value of top-16 bits, outputs the bits
__device__ __forceinline__ float bf_hi(float v, short* bits) {
  unsigned u = __float_as_uint(v);
  *bits = (short)(u >> 16);
  return __uint_as_float(u & 0xffff0000u);
}

// ---- prep: split e into 3 bf16 limbs (k-major slabs) + fused ||e||^2 ----
// eT[limb] flat bf16 idx = (s*2+h)*8192 + c*8 + i   (k = s*16+h*8+i)
__global__ __launch_bounds__(256) void vq_prep_e(
    const float* __restrict__ e, short* __restrict__ e1,
    short* __restrict__ e2, short* __restrict__ e3, float* __restrict__ en)
{
  __shared__ float el[32 * NC];
  const int t = threadIdx.x, cb = blockIdx.x;
  {
    const int r = t >> 3, cc = (t & 7) * 32;
    const float* er = e + (size_t)(cb * 32 + r) * NC + cc;
    float* dst = el + r * NC + cc;
    float ss = 0.f;
    #pragma unroll
    for (int i = 0; i < 8; ++i) {
      float4 v = *(const float4*)(er + i * 4);
      *(float4*)(dst + i * 4) = v;
      ss += v.x * v.x + v.y * v.y + v.z * v.z + v.w * v.w;
    }
    #pragma unroll
    for (int off = 1; off < 8; off <<= 1) ss += __shfl_xor(ss, off, 64);
    if ((t & 7) == 0) en[cb * 32 + r] = ss;       // 8 threads/row share a wave
  }
  __syncthreads();
  const int s = t >> 4, h = (t >> 3) & 1, rb = (t & 7) * 4;
  const int kb = s * 16 + h * 8;
  #pragma unroll
  for (int rr = 0; rr < 4; ++rr) {
    short8v p1, p2, p3;
    #pragma unroll
    for (int ii = 0; ii < 8; ++ii) {
      float v = el[(rb + rr) * NC + kb + ii];
      short b1, b2, b3;
      float f1 = bf_hi(v, &b1);
      float r1 = v - f1;
      float f2 = bf_hi(r1, &b2);
      float r2 = r1 - f2;
      bf_hi(r2, &b3);
      p1[ii] = b1; p2[ii] = b2; p3[ii] = b3;
    }
    size_t off = (size_t)(s * 2 + h) * 8192 + (size_t)(cb * 32 + rb + rr) * 8;
    *(short8v*)(e1 + off) = p1;
    *(short8v*)(e2 + off) = p2;
    *(short8v*)(e3 + off) = p3;
  }
}

// A-fragment load: z-limb LDS layout off = s*512 + half*256 + row*8
#define LOAD_A(dst, s_) {                                               \
    const int aoff_ = (s_) * 512 + half * 256 + l31 * 8;                \
    dst[0] = *(const bf16x8*)&zl1[aoff_];                               \
    dst[1] = *(const bf16x8*)&zl2[aoff_];                               \
    dst[2] = *(const bf16x8*)&zl3[aoff_]; }

// B-fragment load: e-limb layout (s*2+half)*8192 + code*8
#define LOAD_B(dst, s_) {                                               \
    const size_t bb_ = (size_t)((s_) * 2 + half) * 8192                 \
                     + (size_t)(nq * 128 + l31) * 8;                    \
    _Pragma("unroll")                                                   \
    for (int t_ = 0; t_ < 4; ++t_) {                                    \
      const size_t bo_ = bb_ + (size_t)(t_ * 32) * 8;                   \
      dst[t_][0] = *(const bf16x8*)(eT1 + bo_);                         \
      dst[t_][1] = *(const bf16x8*)(eT2 + bo_);                         \
      dst[t_][2] = *(const bf16x8*)(eT3 + bo_); } }

#define MFMA_STEP(za, eb) {                                                        \
    _Pragma("unroll")                                                              \
    for (int t_ = 0; t_ < 4; ++t_) {                                               \
      acc[t_] = __builtin_amdgcn_mfma_f32_32x32x16_bf16(za[0], eb[t_][0], acc[t_], 0, 0, 0); \
      acc[t_] = __builtin_amdgcn_mfma_f32_32x32x16_bf16(za[1], eb[t_][0], acc[t_], 0, 0, 0); \
      acc[t_] = __builtin_amdgcn_mfma_f32_32x32x16_bf16(za[2], eb[t_][0], acc[t_], 0, 0, 0); \
      acc[t_] = __builtin_amdgcn_mfma_f32_32x32x16_bf16(za[0], eb[t_][1], acc[t_], 0, 0, 0); \
      acc[t_] = __builtin_amdgcn_mfma_f32_32x32x16_bf16(za[1], eb[t_][1], acc[t_], 0, 0, 0); \
      acc[t_] = __builtin_amdgcn_mfma_f32_32x32x16_bf16(za[0], eb[t_][2], acc[t_], 0, 0, 0); } }

// ---- main: fused limb-split + 6-product MFMA distances, 32 rows/block ----
// 512 threads = 8 waves, 2 waves/SIMD (256-VGPR budget): wave nq owns 128 codes.
// K-loop: named ping-pong register double-buffer (no dynamic indexing, rule #20).
__global__ __launch_bounds__(512, 2) void vq_main_fused(
    const float* __restrict__ z,
    const short* __restrict__ eT1, const short* __restrict__ eT2, const short* __restrict__ eT3,
    const float* __restrict__ en, const float* __restrict__ mask,
    float* __restrict__ hist, float* __restrict__ idxf)
{
  __shared__ short zl1[8192], zl2[8192], zl3[8192];  // 48 KB: 32 rows x 256 k limbs
  __shared__ float pmv[32][8];
  __shared__ int   pmi[32][8];
  __shared__ float psum[32][8];
  __shared__ float mfin[32];
  __shared__ float wrow[32];

  const int tid  = threadIdx.x;
  const int lane = tid & 63, wv = tid >> 6;
  const int l31  = lane & 31, half = lane >> 5;
  const int nq   = wv;
  const int b = blockIdx.x, row0 = b * 32;

  // ---- conversion: z rows -> 3 limb LDS buffers (one barrier) ----
  {
    const int s = tid >> 5, r = tid & 31;          // thread owns (slab s, row r), 16 k
    const float* zp = z + (size_t)(row0 + r) * NC + s * 16;
    float v[16];
    #pragma unroll
    for (int i = 0; i < 4; ++i) *(float4*)(v + i * 4) = *(const float4*)(zp + i * 4);
    #pragma unroll
    for (int hh = 0; hh < 2; ++hh) {
      short8v p1, p2, p3;
      #pragma unroll
      for (int ii = 0; ii < 8; ++ii) {
        float x = v[hh * 8 + ii];
        short b1, b2, b3;
        float f1 = bf_hi(x, &b1);
        float r1 = x - f1;
        float f2 = bf_hi(r1, &b2);
        float r2 = r1 - f2;
        bf_hi(r2, &b3);
        p1[ii] = b1; p2[ii] = b2; p3[ii] = b3;
      }
      const int off = s * 512 + hh * 256 + r * 8;
      *(short8v*)&zl1[off] = p1;
      *(short8v*)&zl2[off] = p2;
      *(short8v*)&zl3[off] = p3;
    }
  }
  __syncthreads();

  f32x16 acc[4];
  #pragma unroll
  for (int t = 0; t < 4; ++t)
    #pragma unroll
    for (int r = 0; r < 16; ++r) acc[t][r] = 0.f;

  // ---- K-loop: named ping-pong double buffers, 2 steps/iter ----
  bf16x8 zA[3], zB[3];       // A limb frags (index = literal limb only)
  bf16x8 eA[4][3], eB[4][3]; // B frags [tile][limb] (compile-time idx only)
  LOAD_A(zA, 0); LOAD_B(eA, 0);
  #pragma unroll
  for (int s = 0; s < 16; s += 2) {
    LOAD_A(zB, s + 1); LOAD_B(eB, s + 1);    // prefetch odd step
    MFMA_STEP(zA, eA);                        // compute even step
    if (s < 14) { LOAD_A(zA, s + 2); LOAD_B(eA, s + 2); }  // prefetch next even
    MFMA_STEP(zB, eB);                        // compute odd step
  }

  // ---- epilogue: s = ||e||^2 - 2*dot ----
  // C/D layout: col(code) = l31, row = (r&3) + 8*(r>>2) + 4*half
  float enr[4];
  #pragma unroll
  for (int t = 0; t < 4; ++t) enr[t] = en[nq * 128 + t * 32 + l31];
  #pragma unroll
  for (int t = 0; t < 4; ++t)
    #pragma unroll
    for (int r = 0; r < 16; ++r) acc[t][r] = fmaf(-2.f, acc[t][r], enr[t]);

  // per-row argmin over this wave's 128 codes
  float bv[16]; int bi[16];
  #pragma unroll
  for (int r = 0; r < 16; ++r) {
    bv[r] = acc[0][r]; bi[r] = nq * 128 + l31;
    #pragma unroll
    for (int t = 1; t < 4; ++t) {
      float vv = acc[t][r]; int cc = nq * 128 + t * 32 + l31;
      if (vv < bv[r]) { bv[r] = vv; bi[r] = cc; }
    }
    #pragma unroll
    for (int off = 1; off <= 16; off <<= 1) {
      float ov = __shfl_xor(bv[r], off, 64);
      int   oi = __shfl_xor(bi[r], off, 64);
      if (ov < bv[r] || (ov == bv[r] && oi < bi[r])) { bv[r] = ov; bi[r] = oi; }
    }
  }
  if (l31 == 0) {
    #pragma unroll
    for (int r = 0; r < 16; ++r) {
      int rowb = (r & 3) + 8 * (r >> 2) + 4 * half;
      pmv[rowb][nq] = bv[r]; pmi[rowb][nq] = bi[r];
    }
  }
  __syncthreads();
  if (tid < 32) {
    float mv = pmv[tid][0]; int mi = pmi[tid][0];
    #pragma unroll
    for (int w = 1; w < 8; ++w) {
      float v = pmv[tid][w]; int i2 = pmi[tid][w];
      if (v < mv || (v == mv && i2 < mi)) { mv = v; mi = i2; }
    }
    mfin[tid] = mv;
    idxf[row0 + tid] = (float)mi;
  }
  __syncthreads();

  // softmax: p = exp(m_row - s), row sums, weights
  #pragma unroll
  for (int r = 0; r < 16; ++r) {
    const int rowb = (r & 3) + 8 * (r >> 2) + 4 * half;
    float m = mfin[rowb];
    float s0 = 0.f;
    #pragma unroll
    for (int t = 0; t < 4; ++t) {
      float p = __expf(m - acc[t][r]);
      acc[t][r] = p; s0 += p;
    }
    #pragma unroll
    for (int off = 1; off <= 16; off <<= 1) s0 += __shfl_xor(s0, off, 64);
    if (l31 == 0) psum[rowb][nq] = s0;
  }
  __syncthreads();
  if (tid < 32) {
    float s0 = 0.f;
    #pragma unroll
    for (int w = 0; w < 8; ++w) s0 += psum[tid][w];
    wrow[tid] = mask[row0 + tid] / s0;
  }
  __syncthreads();

  // hist: per code, sum wgt*p over the block's 32 rows; atomic-combine
  #pragma unroll
  for (int t = 0; t < 4; ++t) {
    float h = 0.f;
    #pragma unroll
    for (int r = 0; r < 16; ++r)
      h = fmaf(wrow[(r & 3) + 8 * (r >> 2) + 4 * half], acc[t][r], h);
    h += __shfl_xor(h, 32, 64);
    if (half == 0 && h > 1e-12f) atomicAdd(&hist[nq * 128 + t * 32 + l31], h);
  }
}

// ---- gather z_q (float4 grid-stride) + commitment & mask partials ----
__global__ __launch_bounds__(256) void vq_gather(
    const float* __restrict__ z, const float* __restrict__ e,
    const float* __restrict__ mask, const float* __restrict__ idxf,
    float* __restrict__ zq, float* __restrict__ cpart, float* __restrict__ mpart)
{
  const int tid = threadIdx.x, bid = blockIdx.x;
  float cacc = 0.f, macc = 0.f;
  #pragma unroll
  for (int it = 0; it < 4; ++it) {
    int id  = bid * 1024 + it * 256 + tid;
    int row = id >> 6;
    int c4  = (id & 63) << 2;
    int idx = (int)idxf[row];
    float mv = mask[row];
    float4 zv = *(const float4*)(z + (size_t)row * NC + c4);
    float4 qv;
    if (mv == 0.0f) {
      qv = *(const float4*)(e + c4);
    } else {
      float4 ev = *(const float4*)(e + (size_t)idx * NC + c4);
      qv = make_float4(ev.x * mv, ev.y * mv, ev.z * mv, ev.w * mv);
    }
    *(float4*)(zq + (size_t)row * NC + c4) = qv;
    float dx = zv.x - qv.x, dy = zv.y - qv.y, dz = zv.z - qv.z, dw = zv.w - qv.w;
    cacc += (dx * dx + dy * dy + dz * dz + dw * dw) * mv;
    macc += mv;                                   // each row counted 64x
  }
  #pragma unroll
  for (int off = 32; off; off >>= 1) {
    cacc += __shfl_down(cacc, off, 64);
    macc += __shfl_down(macc, off, 64);
  }
  __shared__ float w4[4], m4[4];
  if ((tid & 63) == 0) { w4[tid >> 6] = cacc; m4[tid >> 6] = macc; }
  __syncthreads();
  if (tid == 0) {
    cpart[bid] = w4[0] + w4[1] + w4[2] + w4[3];
    mpart[bid] = (m4[0] + m4[1] + m4[2] + m4[3]) * (1.0f / 64.0f);
  }
}

// ---- run-length keep + prefix scan per batch ----
__global__ void vq_scan(const float* __restrict__ idxf, unsigned short* __restrict__ ord,
                        int* __restrict__ Kc) {
  int b = blockIdx.x, t = threadIdx.x;
  const float* ix = idxf + b * NT;
  int flags[8]; int cnt = 0; int base = t * 8;
  #pragma unroll
  for (int i = 0; i < 8; ++i) {
    int g = base + i;
    int k = (g == 0) ? 1 : (ix[g] != ix[g - 1] ? 1 : 0);
    flags[i] = k; cnt += k;
  }
  int lane = t & 63, wv = t >> 6;
  int scan = cnt;
  for (int off = 1; off < 64; off <<= 1) {
    int v = __shfl_up(scan, off, 64);
    if (lane >= off) scan += v;
  }
  __shared__ int wsum[4];
  if (lane == 63) wsum[wv] = scan;
  __syncthreads();
  int woff = 0;
  for (int w = 0; w < wv; ++w) woff += wsum[w];
  int pos = woff + scan - cnt;
  #pragma unroll
  for (int i = 0; i < 8; ++i) {
    if (flags[i]) { ord[b * NT + pos] = (unsigned short)(base + i); ++pos; }
  }
  if (t == 255) Kc[b] = woff + scan;
}

// ---- compact kept rows to front, pad rest with e[0] ----
__global__ __launch_bounds__(256) void vq_disc(
    const float* __restrict__ zq, const float* __restrict__ e,
    const unsigned short* __restrict__ ord, const int* __restrict__ Kc,
    float* __restrict__ disc)
{
  const int tid = threadIdx.x, bid = blockIdx.x;
  #pragma unroll
  for (int it = 0; it < 2; ++it) {
    int id  = bid * 512 + it * 256 + tid;
    int row = id >> 6;
    int c4  = (id & 63) << 2;
    int b   = row >> 11;
    int j   = row & (NT - 1);
    int K   = Kc[b];
    float4 v;
    if (j < K) {
      int src = ord[(b << 11) + j];
      v = *(const float4*)(zq + ((size_t)(b << 11) + src) * NC + c4);
    } else {
      v = *(const float4*)(e + c4);
    }
    *(float4*)(disc + (size_t)row * NC + c4) = v;
  }
}

// ---- losses ----
__global__ void vq_final(const float* __restrict__ hist, const float* __restrict__ cpart,
                         const float* __restrict__ mpart, float* __restrict__ out) {
  int t = threadIdx.x;
  double csum = 0, msum = 0, hsum = 0;
  #pragma unroll
  for (int i = 0; i < 4; ++i) {
    csum += (double)cpart[i * 256 + t];
    msum += (double)mpart[i * 256 + t];
  }
  double h[4];
  #pragma unroll
  for (int i = 0; i < 4; ++i) { h[i] = (double)hist[i * 256 + t]; hsum += h[i]; }
  #pragma unroll
  for (int off = 32; off; off >>= 1) {
    csum += __shfl_down(csum, off, 64);
    msum += __shfl_down(msum, off, 64);
    hsum += __shfl_down(hsum, off, 64);
  }
  __shared__ double wc[4], wm[4], wh[4];
  __shared__ double tots[3];
  if ((t & 63) == 0) { int w = t >> 6; wc[w] = csum; wm[w] = msum; wh[w] = hsum; }
  __syncthreads();
  if (t == 0) {
    tots[0] = wc[0] + wc[1] + wc[2] + wc[3];
    tots[1] = wm[0] + wm[1] + wm[2] + wm[3];
    tots[2] = wh[0] + wh[1] + wh[2] + wh[3];
  }
  __syncthreads();
  double tot = tots[2] + 1e-8;
  double dv = 0;
  #pragma unroll
  for (int i = 0; i < 4; ++i) {
    double p = h[i] / tot;
    dv += p * log(p * 1024.0 + 1e-8);
  }
  #pragma unroll
  for (int off = 32; off; off >>= 1) dv += __shfl_down(dv, off, 64);
  if ((t & 63) == 0) wc[t >> 6] = dv;
  __syncthreads();
  if (t == 0) {
    out[1] = (float)(wc[0] + wc[1] + wc[2] + wc[3]);
    out[0] = (float)(tots[0] / (tots[1] * 256.0));
  }
}

extern "C" void kernel_launch(void* const* d_in, const int* in_sizes, int n_in,
                              void* d_out, int out_size, void* d_ws, size_t ws_size,
                              hipStream_t stream) {
  if (ws_size < (size_t)WS_REQ) return;

  const float* z    = (const float*)d_in[0];
  const float* e    = (const float*)d_in[1];
  const float* mask = (const float*)d_in[2];
  float* out = (float*)d_out;
  char* ws = (char*)d_ws;

  float*          hist  = (float*)(ws + HIST_OFF);
  float*          en    = (float*)(ws + EN_OFF);
  float*          cpart = (float*)(ws + CPART_OFF);
  float*          mpart = (float*)(ws + MPART_OFF);
  unsigned short* ord   = (unsigned short*)(ws + ORD_OFF);
  int*            Kc    = (int*)(ws + KC_OFF);

  float* zq   = out + 2;
  float* disc = out + 2 + (size_t)BT * NC;
  float* idxf = out + 2 + (size_t)2 * BT * NC;

  // e-limb scratch lives at the start of the disc output region (1.5 MB of
  // 16.8 MB); consumed by vq_main_fused, overwritten later by vq_disc.
  short* e1 = (short*)disc;
  short* e2 = e1 + (size_t)NV * NC;
  short* e3 = e2 + (size_t)NV * NC;

  hipMemsetAsync(ws + HIST_OFF, 0, 4096, stream);
  vq_prep_e    <<<32, 256, 0, stream>>>(e, e1, e2, e3, en);
  vq_main_fused<<<512, 512, 0, stream>>>(z, e1, e2, e3, en, mask, hist, idxf);
  vq_gather    <<<1024, 256, 0, stream>>>(z, e, mask, idxf, zq, cpart, mpart);
  vq_scan      <<<NB, 256, 0, stream>>>(idxf, ord, Kc);
  vq_disc      <<<2048, 256, 0, stream>>>(zq, e, ord, Kc, disc);
  vq_final     <<<1, NC, 0, stream>>>(hist, cpart, mpart, out);
}

// Round 13
// 174.145 us; speedup vs baseline: 1.0599x; 1.0599x over previous
//
#include <hip/hip_runtime.h>
#include <math.h>

#define NB 8
#define NT 2048
#define NC 256
#define NV 1024
#define BT (NB*NT)   // 16384 rows

typedef __attribute__((ext_vector_type(8)))  short bf16x8;
typedef __attribute__((ext_vector_type(8)))  short short8v;
typedef __attribute__((ext_vector_type(16))) float f32x16;

// ---- workspace byte offsets (total: 49,184 B; ws >= 77,856 proven) ----
#define HIST_OFF  0        // float[1024] (zeroed)
#define EN_OFF    4096     // float[1024] ||e||^2
#define CPART_OFF 8192     // float[1024] commitment partials
#define MPART_OFF 12288    // float[1024] mask partials
#define ORD_OFF   16384    // ushort[16384] (positions < 2048)
#define KC_OFF    49152    // int[8]
#define WS_REQ    49184

// truncated-bf16 limb: returns float value of top-16 bits, outputs the bits
__device__ __forceinline__ float bf_hi(float v, short* bits) {
  unsigned u = __float_as_uint(v);
  *bits = (short)(u >> 16);
  return __uint_as_float(u & 0xffff0000u);
}

// ---- prep: split e into 3 bf16 limbs (k-major slabs) + fused ||e||^2 ----
// eT[limb] flat bf16 idx = (s*2+h)*8192 + c*8 + i   (k = s*16+h*8+i)
__global__ __launch_bounds__(256) void vq_prep_e(
    const float* __restrict__ e, short* __restrict__ e1,
    short* __restrict__ e2, short* __restrict__ e3, float* __restrict__ en)
{
  __shared__ float el[32 * NC];
  const int t = threadIdx.x, cb = blockIdx.x;
  {
    const int r = t >> 3, cc = (t & 7) * 32;
    const float* er = e + (size_t)(cb * 32 + r) * NC + cc;
    float* dst = el + r * NC + cc;
    float ss = 0.f;
    #pragma unroll
    for (int i = 0; i < 8; ++i) {
      float4 v = *(const float4*)(er + i * 4);
      *(float4*)(dst + i * 4) = v;
      ss += v.x * v.x + v.y * v.y + v.z * v.z + v.w * v.w;
    }
    #pragma unroll
    for (int off = 1; off < 8; off <<= 1) ss += __shfl_xor(ss, off, 64);
    if ((t & 7) == 0) en[cb * 32 + r] = ss;       // 8 threads/row share a wave
  }
  __syncthreads();
  const int s = t >> 4, h = (t >> 3) & 1, rb = (t & 7) * 4;
  const int kb = s * 16 + h * 8;
  #pragma unroll
  for (int rr = 0; rr < 4; ++rr) {
    short8v p1, p2, p3;
    #pragma unroll
    for (int ii = 0; ii < 8; ++ii) {
      float v = el[(rb + rr) * NC + kb + ii];
      short b1, b2, b3;
      float f1 = bf_hi(v, &b1);
      float r1 = v - f1;
      float f2 = bf_hi(r1, &b2);
      float r2 = r1 - f2;
      bf_hi(r2, &b3);
      p1[ii] = b1; p2[ii] = b2; p3[ii] = b3;
    }
    size_t off = (size_t)(s * 2 + h) * 8192 + (size_t)(cb * 32 + rb + rr) * 8;
    *(short8v*)(e1 + off) = p1;
    *(short8v*)(e2 + off) = p2;
    *(short8v*)(e3 + off) = p3;
  }
}

// A-fragment load: z-limb LDS layout off = s*512 + half*256 + row*8
#define LOAD_A(dst, s_) {                                               \
    const int aoff_ = (s_) * 512 + half * 256 + l31 * 8;                \
    dst[0] = *(const bf16x8*)&zl1[aoff_];                               \
    dst[1] = *(const bf16x8*)&zl2[aoff_];                               \
    dst[2] = *(const bf16x8*)&zl3[aoff_]; }

// B-fragment load: e-limb layout (s*2+half)*8192 + code*8
#define LOAD_B(dst, s_) {                                               \
    const size_t bb_ = (size_t)((s_) * 2 + half) * 8192                 \
                     + (size_t)(nq * 128 + l31) * 8;                    \
    _Pragma("unroll")                                                   \
    for (int t_ = 0; t_ < 4; ++t_) {                                    \
      const size_t bo_ = bb_ + (size_t)(t_ * 32) * 8;                   \
      dst[t_][0] = *(const bf16x8*)(eT1 + bo_);                         \
      dst[t_][1] = *(const bf16x8*)(eT2 + bo_);                         \
      dst[t_][2] = *(const bf16x8*)(eT3 + bo_); } }

#define MFMA_STEP(za, eb) {                                                        \
    _Pragma("unroll")                                                              \
    for (int t_ = 0; t_ < 4; ++t_) {                                               \
      acc[t_] = __builtin_amdgcn_mfma_f32_32x32x16_bf16(za[0], eb[t_][0], acc[t_], 0, 0, 0); \
      acc[t_] = __builtin_amdgcn_mfma_f32_32x32x16_bf16(za[1], eb[t_][0], acc[t_], 0, 0, 0); \
      acc[t_] = __builtin_amdgcn_mfma_f32_32x32x16_bf16(za[2], eb[t_][0], acc[t_], 0, 0, 0); \
      acc[t_] = __builtin_amdgcn_mfma_f32_32x32x16_bf16(za[0], eb[t_][1], acc[t_], 0, 0, 0); \
      acc[t_] = __builtin_amdgcn_mfma_f32_32x32x16_bf16(za[1], eb[t_][1], acc[t_], 0, 0, 0); \
      acc[t_] = __builtin_amdgcn_mfma_f32_32x32x16_bf16(za[0], eb[t_][2], acc[t_], 0, 0, 0); } }

// ---- main: fused limb-split + 6-product MFMA distances, 32 rows/block ----
// 512 threads = 8 waves, 2 waves/SIMD (256-VGPR budget): wave nq owns 128 codes.
// K-loop: ping-pong register dbuf; sched_barrier(0) pins prefetch BEFORE MFMA
// cluster (compiler otherwise sinks loads to uses, collapsing the dbuf — r12).
__global__ __launch_bounds__(512, 2) void vq_main_fused(
    const float* __restrict__ z,
    const short* __restrict__ eT1, const short* __restrict__ eT2, const short* __restrict__ eT3,
    const float* __restrict__ en, const float* __restrict__ mask,
    float* __restrict__ hist, float* __restrict__ idxf)
{
  __shared__ short zl1[8192], zl2[8192], zl3[8192];  // 48 KB: 32 rows x 256 k limbs
  __shared__ float pmv[32][8];
  __shared__ int   pmi[32][8];
  __shared__ float psum[32][8];
  __shared__ float mfin[32];
  __shared__ float wrow[32];

  const int tid  = threadIdx.x;
  const int lane = tid & 63, wv = tid >> 6;
  const int l31  = lane & 31, half = lane >> 5;
  const int nq   = wv;
  const int b = blockIdx.x, row0 = b * 32;

  // ---- conversion: z rows -> 3 limb LDS buffers (one barrier) ----
  {
    const int s = tid >> 5, r = tid & 31;          // thread owns (slab s, row r), 16 k
    const float* zp = z + (size_t)(row0 + r) * NC + s * 16;
    float v[16];
    #pragma unroll
    for (int i = 0; i < 4; ++i) *(float4*)(v + i * 4) = *(const float4*)(zp + i * 4);
    #pragma unroll
    for (int hh = 0; hh < 2; ++hh) {
      short8v p1, p2, p3;
      #pragma unroll
      for (int ii = 0; ii < 8; ++ii) {
        float x = v[hh * 8 + ii];
        short b1, b2, b3;
        float f1 = bf_hi(x, &b1);
        float r1 = x - f1;
        float f2 = bf_hi(r1, &b2);
        float r2 = r1 - f2;
        bf_hi(r2, &b3);
        p1[ii] = b1; p2[ii] = b2; p3[ii] = b3;
      }
      const int off = s * 512 + hh * 256 + r * 8;
      *(short8v*)&zl1[off] = p1;
      *(short8v*)&zl2[off] = p2;
      *(short8v*)&zl3[off] = p3;
    }
  }
  __syncthreads();

  f32x16 acc[4];
  #pragma unroll
  for (int t = 0; t < 4; ++t)
    #pragma unroll
    for (int r = 0; r < 16; ++r) acc[t][r] = 0.f;

  // ---- K-loop: ping-pong dbuf, order pinned so prefetch overlaps MFMA ----
  bf16x8 zA[3], zB[3];       // A limb frags (index = literal limb only)
  bf16x8 eA[4][3], eB[4][3]; // B frags [tile][limb] (compile-time idx only)
  LOAD_A(zA, 0); LOAD_B(eA, 0);
  #pragma unroll
  for (int s = 0; s < 16; s += 2) {
    LOAD_A(zB, s + 1); LOAD_B(eB, s + 1);    // prefetch odd step
    __builtin_amdgcn_sched_barrier(0);        // pin: loads issued before MFMAs
    __builtin_amdgcn_s_setprio(1);
    MFMA_STEP(zA, eA);                        // compute even step
    __builtin_amdgcn_s_setprio(0);
    if (s < 14) { LOAD_A(zA, s + 2); LOAD_B(eA, s + 2); }  // prefetch next even
    __builtin_amdgcn_sched_barrier(0);
    __builtin_amdgcn_s_setprio(1);
    MFMA_STEP(zB, eB);                        // compute odd step
    __builtin_amdgcn_s_setprio(0);
  }

  // ---- epilogue: s = ||e||^2 - 2*dot ----
  // C/D layout: col(code) = l31, row = (r&3) + 8*(r>>2) + 4*half
  float enr[4];
  #pragma unroll
  for (int t = 0; t < 4; ++t) enr[t] = en[nq * 128 + t * 32 + l31];
  #pragma unroll
  for (int t = 0; t < 4; ++t)
    #pragma unroll
    for (int r = 0; r < 16; ++r) acc[t][r] = fmaf(-2.f, acc[t][r], enr[t]);

  // per-row argmin over this wave's 128 codes
  float bv[16]; int bi[16];
  #pragma unroll
  for (int r = 0; r < 16; ++r) {
    bv[r] = acc[0][r]; bi[r] = nq * 128 + l31;
    #pragma unroll
    for (int t = 1; t < 4; ++t) {
      float vv = acc[t][r]; int cc = nq * 128 + t * 32 + l31;
      if (vv < bv[r]) { bv[r] = vv; bi[r] = cc; }
    }
    #pragma unroll
    for (int off = 1; off <= 16; off <<= 1) {
      float ov = __shfl_xor(bv[r], off, 64);
      int   oi = __shfl_xor(bi[r], off, 64);
      if (ov < bv[r] || (ov == bv[r] && oi < bi[r])) { bv[r] = ov; bi[r] = oi; }
    }
  }
  if (l31 == 0) {
    #pragma unroll
    for (int r = 0; r < 16; ++r) {
      int rowb = (r & 3) + 8 * (r >> 2) + 4 * half;
      pmv[rowb][nq] = bv[r]; pmi[rowb][nq] = bi[r];
    }
  }
  __syncthreads();
  if (tid < 32) {
    float mv = pmv[tid][0]; int mi = pmi[tid][0];
    #pragma unroll
    for (int w = 1; w < 8; ++w) {
      float v = pmv[tid][w]; int i2 = pmi[tid][w];
      if (v < mv || (v == mv && i2 < mi)) { mv = v; mi = i2; }
    }
    mfin[tid] = mv;
    idxf[row0 + tid] = (float)mi;
  }
  __syncthreads();

  // softmax: p = exp(m_row - s), row sums, weights
  #pragma unroll
  for (int r = 0; r < 16; ++r) {
    const int rowb = (r & 3) + 8 * (r >> 2) + 4 * half;
    float m = mfin[rowb];
    float s0 = 0.f;
    #pragma unroll
    for (int t = 0; t < 4; ++t) {
      float p = __expf(m - acc[t][r]);
      acc[t][r] = p; s0 += p;
    }
    #pragma unroll
    for (int off = 1; off <= 16; off <<= 1) s0 += __shfl_xor(s0, off, 64);
    if (l31 == 0) psum[rowb][nq] = s0;
  }
  __syncthreads();
  if (tid < 32) {
    float s0 = 0.f;
    #pragma unroll
    for (int w = 0; w < 8; ++w) s0 += psum[tid][w];
    wrow[tid] = mask[row0 + tid] / s0;
  }
  __syncthreads();

  // hist: per code, sum wgt*p over the block's 32 rows; atomic-combine
  #pragma unroll
  for (int t = 0; t < 4; ++t) {
    float h = 0.f;
    #pragma unroll
    for (int r = 0; r < 16; ++r)
      h = fmaf(wrow[(r & 3) + 8 * (r >> 2) + 4 * half], acc[t][r], h);
    h += __shfl_xor(h, 32, 64);
    if (half == 0 && h > 1e-12f) atomicAdd(&hist[nq * 128 + t * 32 + l31], h);
  }
}

// ---- fused: gather z_q + partials (blocks 0..1023) | run-length scan (1024..1031) ----
__global__ __launch_bounds__(256) void vq_gather_scan(
    const float* __restrict__ z, const float* __restrict__ e,
    const float* __restrict__ mask, const float* __restrict__ idxf,
    float* __restrict__ zq, float* __restrict__ cpart, float* __restrict__ mpart,
    unsigned short* __restrict__ ord, int* __restrict__ Kc)
{
  const int tid = threadIdx.x, bid = blockIdx.x;
  if (bid < 1024) {
    float cacc = 0.f, macc = 0.f;
    #pragma unroll
    for (int it = 0; it < 4; ++it) {
      int id  = bid * 1024 + it * 256 + tid;
      int row = id >> 6;
      int c4  = (id & 63) << 2;
      int idx = (int)idxf[row];
      float mv = mask[row];
      float4 zv = *(const float4*)(z + (size_t)row * NC + c4);
      float4 qv;
      if (mv == 0.0f) {
        qv = *(const float4*)(e + c4);
      } else {
        float4 ev = *(const float4*)(e + (size_t)idx * NC + c4);
        qv = make_float4(ev.x * mv, ev.y * mv, ev.z * mv, ev.w * mv);
      }
      *(float4*)(zq + (size_t)row * NC + c4) = qv;
      float dx = zv.x - qv.x, dy = zv.y - qv.y, dz = zv.z - qv.z, dw = zv.w - qv.w;
      cacc += (dx * dx + dy * dy + dz * dz + dw * dw) * mv;
      macc += mv;                                 // each row counted 64x
    }
    #pragma unroll
    for (int off = 32; off; off >>= 1) {
      cacc += __shfl_down(cacc, off, 64);
      macc += __shfl_down(macc, off, 64);
    }
    __shared__ float w4[4], m4[4];
    if ((tid & 63) == 0) { w4[tid >> 6] = cacc; m4[tid >> 6] = macc; }
    __syncthreads();
    if (tid == 0) {
      cpart[bid] = w4[0] + w4[1] + w4[2] + w4[3];
      mpart[bid] = (m4[0] + m4[1] + m4[2] + m4[3]) * (1.0f / 64.0f);
    }
  } else {
    const int b = bid - 1024;
    const float* ix = idxf + b * NT;
    int flags[8]; int cnt = 0; int base = tid * 8;
    #pragma unroll
    for (int i = 0; i < 8; ++i) {
      int g = base + i;
      int k = (g == 0) ? 1 : (ix[g] != ix[g - 1] ? 1 : 0);
      flags[i] = k; cnt += k;
    }
    int lane = tid & 63, wv = tid >> 6;
    int scan = cnt;
    for (int off = 1; off < 64; off <<= 1) {
      int v = __shfl_up(scan, off, 64);
      if (lane >= off) scan += v;
    }
    __shared__ int wsum[4];
    if (lane == 63) wsum[wv] = scan;
    __syncthreads();
    int woff = 0;
    for (int w = 0; w < wv; ++w) woff += wsum[w];
    int pos = woff + scan - cnt;                  // exclusive prefix
    #pragma unroll
    for (int i = 0; i < 8; ++i) {
      if (flags[i]) { ord[b * NT + pos] = (unsigned short)(base + i); ++pos; }
    }
    if (tid == 255) Kc[b] = woff + scan;
  }
}

// ---- fused: compact kept rows (blocks 0..2047) | losses (block 2048) ----
__global__ __launch_bounds__(256) void vq_disc_final(
    const float* __restrict__ zq, const float* __restrict__ e,
    const unsigned short* __restrict__ ord, const int* __restrict__ Kc,
    float* __restrict__ disc, const float* __restrict__ hist,
    const float* __restrict__ cpart, const float* __restrict__ mpart,
    float* __restrict__ out)
{
  const int tid = threadIdx.x, bid = blockIdx.x;
  if (bid < 2048) {
    #pragma unroll
    for (int it = 0; it < 2; ++it) {
      int id  = bid * 512 + it * 256 + tid;
      int row = id >> 6;
      int c4  = (id & 63) << 2;
      int b   = row >> 11;
      int j   = row & (NT - 1);
      int K   = Kc[b];
      float4 v;
      if (j < K) {
        int src = ord[(b << 11) + j];
        v = *(const float4*)(zq + ((size_t)(b << 11) + src) * NC + c4);
      } else {
        v = *(const float4*)(e + c4);
      }
      *(float4*)(disc + (size_t)row * NC + c4) = v;
    }
  } else {
    int t = tid;
    double csum = 0, msum = 0, hsum = 0;
    #pragma unroll
    for (int i = 0; i < 4; ++i) {
      csum += (double)cpart[i * 256 + t];
      msum += (double)mpart[i * 256 + t];
    }
    double h[4];
    #pragma unroll
    for (int i = 0; i < 4; ++i) { h[i] = (double)hist[i * 256 + t]; hsum += h[i]; }
    #pragma unroll
    for (int off = 32; off; off >>= 1) {
      csum += __shfl_down(csum, off, 64);
      msum += __shfl_down(msum, off, 64);
      hsum += __shfl_down(hsum, off, 64);
    }
    __shared__ double wc[4], wm[4], wh[4];
    __shared__ double tots[3];
    if ((t & 63) == 0) { int w = t >> 6; wc[w] = csum; wm[w] = msum; wh[w] = hsum; }
    __syncthreads();
    if (t == 0) {
      tots[0] = wc[0] + wc[1] + wc[2] + wc[3];
      tots[1] = wm[0] + wm[1] + wm[2] + wm[3];
      tots[2] = wh[0] + wh[1] + wh[2] + wh[3];
    }
    __syncthreads();
    double tot = tots[2] + 1e-8;
    double dv = 0;
    #pragma unroll
    for (int i = 0; i < 4; ++i) {
      double p = h[i] / tot;
      dv += p * log(p * 1024.0 + 1e-8);
    }
    #pragma unroll
    for (int off = 32; off; off >>= 1) dv += __shfl_down(dv, off, 64);
    if ((t & 63) == 0) wc[t >> 6] = dv;
    __syncthreads();
    if (t == 0) {
      out[1] = (float)(wc[0] + wc[1] + wc[2] + wc[3]);
      out[0] = (float)(tots[0] / (tots[1] * 256.0));
    }
  }
}

extern "C" void kernel_launch(void* const* d_in, const int* in_sizes, int n_in,
                              void* d_out, int out_size, void* d_ws, size_t ws_size,
                              hipStream_t stream) {
  if (ws_size < (size_t)WS_REQ) return;

  const float* z    = (const float*)d_in[0];
  const float* e    = (const float*)d_in[1];
  const float* mask = (const float*)d_in[2];
  float* out = (float*)d_out;
  char* ws = (char*)d_ws;

  float*          hist  = (float*)(ws + HIST_OFF);
  float*          en    = (float*)(ws + EN_OFF);
  float*          cpart = (float*)(ws + CPART_OFF);
  float*          mpart = (float*)(ws + MPART_OFF);
  unsigned short* ord   = (unsigned short*)(ws + ORD_OFF);
  int*            Kc    = (int*)(ws + KC_OFF);

  float* zq   = out + 2;
  float* disc = out + 2 + (size_t)BT * NC;
  float* idxf = out + 2 + (size_t)2 * BT * NC;

  // e-limb scratch lives at the start of the disc output region (1.5 MB of
  // 16.8 MB); consumed by vq_main_fused, overwritten later by vq_disc_final.
  short* e1 = (short*)disc;
  short* e2 = e1 + (size_t)NV * NC;
  short* e3 = e2 + (size_t)NV * NC;

  hipMemsetAsync(ws + HIST_OFF, 0, 4096, stream);
  vq_prep_e     <<<32, 256, 0, stream>>>(e, e1, e2, e3, en);
  vq_main_fused <<<512, 512, 0, stream>>>(z, e1, e2, e3, en, mask, hist, idxf);
  vq_gather_scan<<<1032, 256, 0, stream>>>(z, e, mask, idxf, zq, cpart, mpart, ord, Kc);
  vq_disc_final <<<2049, 256, 0, stream>>>(zq, e, ord, Kc, disc, hist, cpart, mpart, out);
}